// Round 6
// baseline (184.444 us; speedup 1.0000x reference)
//
#include <hip/hip_runtime.h>
#include <hip/hip_cooperative_groups.h>
#include <math.h>

namespace cg = cooperative_groups;

#define NATOMS 8192
#define NF 128
#define NH 64
#define NB 8

#define TI 16       // i-atoms per block (phase 1 and phase 2)
#define TJ 256      // j-tile size (LDS)
#define JS 16       // j-slices per block (TI*JS = 256 threads)

// workspace byte offsets
#define OFF_BATCH32 0         // int[NATOMS]     32 KB
#define OFF_Q       32768     // float[NATOMS]   32 KB
#define OFF_GSTART  65536     // int[NB+1]

// ---------------------------------------------------------------------------
// Single cooperative kernel, 512 blocks x 256 threads (2 blocks/CU).
// Phase 1: each block computes q for its 16 atoms (4 waves x 4 atoms/wave,
//          W1 loads shared across the 4 accumulator chains), converts its
//          16 batch entries to int32; block 0 also computes gstart via
//          binary search on the raw (width-detected) batch buffer.
// grid.sync()
// Phase 2: per-block graph-mean preamble + LDS j-tile pair loop + epilogue
//          (identical structure to the R5 pairfin kernel).
// Width detect: sorted non-negative batch => v32[N-1]==0 <=> int64 layout
// (all-zero batch is width-invariant).
// ---------------------------------------------------------------------------
__global__ __launch_bounds__(256, 2) void fused_all_kernel(
    const float* __restrict__ x, const float* __restrict__ W1,
    const float* __restrict__ b1, const float* __restrict__ W2,
    const float* __restrict__ b2, const void* __restrict__ batch_raw,
    const float* __restrict__ pos,
    int* __restrict__ batch32, int* __restrict__ gstart,
    float* __restrict__ q, float* __restrict__ out,
    const float* __restrict__ scr_p, const float* __restrict__ soft_p) {
    __shared__ float4 tile[TJ];
    __shared__ float smean[NB];
    __shared__ float red[4];
    __shared__ float psum[JS * TI];

    const int tid = threadIdx.x;
    const int bid = blockIdx.x;
    const int i0 = bid * TI;

    const int* v32 = (const int*)batch_raw;
    const long long* v64 = (const long long*)batch_raw;
    const bool is64 = (v32[NATOMS - 1] == 0);

    // ---- phase 1: housekeeping -------------------------------------------
    if (tid < TI) {                             // this block's batch32 slice
        const int a = i0 + tid;
        batch32[a] = is64 ? (int)v64[a] : v32[a];
    }
    if (bid == 0 && tid <= NB) {                // gstart binary searches
        if (tid == NB) {
            gstart[NB] = NATOMS;
        } else {
            int lo = 0, hi = NATOMS;            // lower_bound(batch, tid)
            while (lo < hi) {
                int mid = (lo + hi) >> 1;
                int v = is64 ? (int)v64[mid] : v32[mid];
                if (v < tid) lo = mid + 1; else hi = mid;
            }
            gstart[tid] = lo;
        }
    }

    // ---- phase 1: MLP q for 4 atoms per wave (shared W1 loads) -----------
    {
        const int wave = tid >> 6;
        const int lane = tid & 63;
        const int a0 = i0 + wave * 4;
        const float* xr0 = x + (a0 + 0) * NF;
        const float* xr1 = x + (a0 + 1) * NF;
        const float* xr2 = x + (a0 + 2) * NF;
        const float* xr3 = x + (a0 + 3) * NF;
        const float bb = b1[lane];
        float z0 = bb, z1 = bb, z2 = bb, z3 = bb;
#pragma unroll
        for (int f = 0; f < NF; f += 4) {
            const float4 xa = *(const float4*)(xr0 + f);
            const float4 xb = *(const float4*)(xr1 + f);
            const float4 xc = *(const float4*)(xr2 + f);
            const float4 xd = *(const float4*)(xr3 + f);
            const float w0 = W1[(f + 0) * NH + lane];
            const float w1 = W1[(f + 1) * NH + lane];
            const float w2 = W1[(f + 2) * NH + lane];
            const float w3 = W1[(f + 3) * NH + lane];
            z0 = fmaf(xa.x, w0, z0); z1 = fmaf(xb.x, w0, z1);
            z2 = fmaf(xc.x, w0, z2); z3 = fmaf(xd.x, w0, z3);
            z0 = fmaf(xa.y, w1, z0); z1 = fmaf(xb.y, w1, z1);
            z2 = fmaf(xc.y, w1, z2); z3 = fmaf(xd.y, w1, z3);
            z0 = fmaf(xa.z, w2, z0); z1 = fmaf(xb.z, w2, z1);
            z2 = fmaf(xc.z, w2, z2); z3 = fmaf(xd.z, w2, z3);
            z0 = fmaf(xa.w, w3, z0); z1 = fmaf(xb.w, w3, z1);
            z2 = fmaf(xc.w, w3, z2); z3 = fmaf(xd.w, w3, z3);
        }
        const float wl = W2[lane];
        float t0 = wl * (z0 / (1.0f + __expf(-z0)));
        float t1 = wl * (z1 / (1.0f + __expf(-z1)));
        float t2 = wl * (z2 / (1.0f + __expf(-z2)));
        float t3 = wl * (z3 / (1.0f + __expf(-z3)));
#pragma unroll
        for (int m = 32; m >= 1; m >>= 1) {
            t0 += __shfl_xor(t0, m, 64);
            t1 += __shfl_xor(t1, m, 64);
            t2 += __shfl_xor(t2, m, 64);
            t3 += __shfl_xor(t3, m, 64);
        }
        if (lane == 0) {
            const float bo = b2[0];
            q[a0 + 0] = t0 + bo;
            q[a0 + 1] = t1 + bo;
            q[a0 + 2] = t2 + bo;
            q[a0 + 3] = t3 + bo;
        }
    }

    __threadfence();                            // device-scope visibility
    cg::this_grid().sync();

    // ---- phase 2: graph means (per block; spans are contiguous) ----------
    const int gfirst = batch32[i0];
    const int glast = batch32[i0 + TI - 1];
    for (int g = gfirst; g <= glast; ++g) {
        const int s = gstart[g], e = gstart[g + 1];
        float t = 0.0f;
        for (int idx = s + tid; idx < e; idx += 256) t += q[idx];
#pragma unroll
        for (int m = 32; m >= 1; m >>= 1) t += __shfl_xor(t, m, 64);
        if ((tid & 63) == 0) red[tid >> 6] = t;
        __syncthreads();
        if (tid == 0) {
            const int c = e - s;
            smean[g] = (red[0] + red[1] + red[2] + red[3]) /
                       (float)(c > 0 ? c : 1);
        }
        __syncthreads();
    }

    // ---- phase 2: pair loop ----------------------------------------------
    const float scr = *scr_p;
    const float soft = *soft_p;
    const float soft2 = soft * soft;

    const int ii = tid & (TI - 1);
    const int js = tid >> 4;                    // log2(TI) = 4
    const int i = i0 + ii;
    const int gi = batch32[i];
    const int si = gstart[gi];
    const unsigned span = (unsigned)(gstart[gi + 1] - si);
    const float pix = pos[3 * i + 0];
    const float piy = pos[3 * i + 1];
    const float piz = pos[3 * i + 2];

    const int jlo = gstart[gfirst];
    const int jhi = gstart[glast + 1];

    float acc = 0.0f;
    for (int jt = jlo; jt < jhi; jt += TJ) {
        __syncthreads();
        const int jj = jt + tid;
        float4 v;
        if (jj < jhi) {
            v.x = pos[3 * jj + 0];
            v.y = pos[3 * jj + 1];
            v.z = pos[3 * jj + 2];
            v.w = q[jj] - smean[batch32[jj]];
        } else {
            v.x = v.y = v.z = v.w = 0.0f;
        }
        tile[tid] = v;
        __syncthreads();

        const int cnt = min(TJ, jhi - jt);
        const int base = jt - si;
        const int ue = min(js * TI + TI, cnt);
        for (int u = js * TI; u < ue; ++u) {
            const float4 p = tile[u];
            const float dx = p.x - pix;
            const float dy = p.y - piy;
            const float dz = p.z - piz;
            float d2 = fmaf(dx, dx, soft2);
            d2 = fmaf(dy, dy, d2);
            d2 = fmaf(dz, dz, d2);
            const float rinv = rsqrtf(d2);
            const float r = d2 * rinv;
            const float e = __expf(-scr * r);
            const float w = ((unsigned)(base + u) < span) ? p.w : 0.0f;
            acc = fmaf(w * e, rinv, acc);
        }
    }
    psum[js * TI + ii] = acc;
    __syncthreads();

    if (tid < TI) {
        float tot = 0.0f;
#pragma unroll
        for (int k = 0; k < JS; ++k) tot += psum[k * TI + tid];
        const float qn = q[i] - smean[gi];
        const float sa = fabsf(soft);
        const float selfk = __expf(-scr * sa) / sa;
        out[i] = 0.5f * qn * (tot - qn * selfk);
    }
}

extern "C" void kernel_launch(void* const* d_in, const int* in_sizes, int n_in,
                              void* d_out, int out_size, void* d_ws, size_t ws_size,
                              hipStream_t stream) {
    const float* x    = (const float*)d_in[0];
    const float* pos  = (const float*)d_in[1];
    // d_in[2] = cell (unused by reference math for nonperiodic path)
    const float* W1   = (const float*)d_in[3];
    const float* b1   = (const float*)d_in[4];
    const float* W2   = (const float*)d_in[5];
    const float* b2   = (const float*)d_in[6];
    const float* scr  = (const float*)d_in[7];
    const float* soft = (const float*)d_in[8];
    const void*  braw = (const void*)d_in[9];

    char* ws = (char*)d_ws;
    int*   batch32 = (int*)(ws + OFF_BATCH32);
    float* q       = (float*)(ws + OFF_Q);
    int*   gstart  = (int*)(ws + OFF_GSTART);
    float* out     = (float*)d_out;

    void* args[] = {(void*)&x, (void*)&W1, (void*)&b1, (void*)&W2,
                    (void*)&b2, (void*)&braw, (void*)&pos,
                    (void*)&batch32, (void*)&gstart, (void*)&q,
                    (void*)&out, (void*)&scr, (void*)&soft};
    hipLaunchCooperativeKernel((void*)fused_all_kernel, dim3(NATOMS / TI),
                               dim3(256), args, 0, stream);
}

// Round 7
// 103.562 us; speedup vs baseline: 1.7810x; 1.7810x over previous
//
#include <hip/hip_runtime.h>
#include <math.h>

#define NATOMS 8192
#define NF 128
#define NH 64
#define NB 8

#define TI 16       // i-atoms per pairfin block
#define TJ 256      // j-tile size (LDS)
#define JS 16       // j-slices per block (TI*JS = 256 threads)

// workspace byte offsets
#define OFF_BATCH32 0         // int[NATOMS]     32 KB
#define OFF_Q       32768     // float[NATOMS]   32 KB
#define OFF_GSTART  65536     // int[NB+1]

// NOTE (R6 post-mortem): do NOT fuse these two kernels with a cooperative
// grid.sync() — measured +75us of stall (device-scope fence/L2 maintenance
// + spin barrier on 8 XCDs) vs ~5us saved launch gap.

// ---------------------------------------------------------------------------
// fused1: blocks 0..2047 -> q (one wave per atom) + batch32 conversion;
//         block 2048     -> gstart binary searches on the raw batch buffer.
// Width detect: sorted non-negative batch => v32[N-1]==0 <=> int64 layout.
// ---------------------------------------------------------------------------
__global__ __launch_bounds__(256) void fused1_kernel(
    const float* __restrict__ x, const float* __restrict__ W1,
    const float* __restrict__ b1, const float* __restrict__ W2,
    const float* __restrict__ b2, const void* __restrict__ batch_raw,
    int* __restrict__ batch32, int* __restrict__ gstart,
    float* __restrict__ q) {
    const int* v32 = (const int*)batch_raw;
    const long long* v64 = (const long long*)batch_raw;
    const int tid = threadIdx.x;

    if (blockIdx.x == 2048) {                   // gstart block
        const bool is64 = (v32[NATOMS - 1] == 0);
        if (tid <= NB) {
            if (tid == NB) {
                gstart[NB] = NATOMS;
            } else {
                int lo = 0, hi = NATOMS;        // lower_bound(batch, tid)
                while (lo < hi) {
                    int mid = (lo + hi) >> 1;
                    int v = is64 ? (int)v64[mid] : v32[mid];
                    if (v < tid) lo = mid + 1; else hi = mid;
                }
                gstart[tid] = lo;
            }
        }
        return;
    }

    const int gt = blockIdx.x * 256 + tid;
    if (gt < NATOMS) {                          // batch32 conversion (guarded)
        const bool is64 = (v32[NATOMS - 1] == 0);
        batch32[gt] = is64 ? (int)v64[gt] : v32[gt];
    }

    const int atom = gt >> 6;                   // global wave id == atom
    const int lane = tid & 63;

    const float* xr = x + atom * NF;
    float z0 = b1[lane], z1 = 0.0f;             // 2 chains: halve dep latency
#pragma unroll
    for (int f0 = 0; f0 < NF; f0 += 8) {
        const float4 xa = *(const float4*)(xr + f0);
        const float4 xb = *(const float4*)(xr + f0 + 4);
        z0 = fmaf(xa.x, W1[(f0 + 0) * NH + lane], z0);
        z1 = fmaf(xa.y, W1[(f0 + 1) * NH + lane], z1);
        z0 = fmaf(xa.z, W1[(f0 + 2) * NH + lane], z0);
        z1 = fmaf(xa.w, W1[(f0 + 3) * NH + lane], z1);
        z0 = fmaf(xb.x, W1[(f0 + 4) * NH + lane], z0);
        z1 = fmaf(xb.y, W1[(f0 + 5) * NH + lane], z1);
        z0 = fmaf(xb.z, W1[(f0 + 6) * NH + lane], z0);
        z1 = fmaf(xb.w, W1[(f0 + 7) * NH + lane], z1);
    }
    const float z = z0 + z1;
    const float h = z / (1.0f + __expf(-z));    // SiLU
    float t = h * W2[lane];
#pragma unroll
    for (int m = 32; m >= 1; m >>= 1) t += __shfl_xor(t, m, 64);
    if (lane == 0) q[atom] = t + b2[0];
}

// ---------------------------------------------------------------------------
// pairfin: 512 blocks x 256 thr = TI(16) i-atoms x JS(16) j-slices.
// Preamble: per-block graph-sum reduction (batch sorted => contiguous spans)
// replaces a separate gsum kernel. LDS j-tiles hold (pos.xyz, qn). Self
// term included then subtracted analytically; no atomics; writes out[].
// ---------------------------------------------------------------------------
__global__ __launch_bounds__(256) void pairfin_kernel(
    const float* __restrict__ pos, const float* __restrict__ q,
    const int* __restrict__ batch32, const int* __restrict__ gstart,
    float* __restrict__ out,
    const float* __restrict__ scr_p, const float* __restrict__ soft_p) {
    __shared__ float4 tile[TJ];
    __shared__ float smean[NB];
    __shared__ float red[4];
    __shared__ float psum[JS * TI];

    const int tid = threadIdx.x;
    const int ii = tid & (TI - 1);
    const int js = tid >> 4;                    // log2(TI) = 4

    const int i0 = blockIdx.x * TI;
    const int gfirst = batch32[i0];
    const int glast = batch32[i0 + TI - 1];

    // per-block graph mean(s): reduce q over each contiguous graph span
    for (int g = gfirst; g <= glast; ++g) {
        const int s = gstart[g], e = gstart[g + 1];
        float t = 0.0f;
        for (int idx = s + tid; idx < e; idx += 256) t += q[idx];
#pragma unroll
        for (int m = 32; m >= 1; m >>= 1) t += __shfl_xor(t, m, 64);
        if ((tid & 63) == 0) red[tid >> 6] = t;
        __syncthreads();
        if (tid == 0) {
            const int c = e - s;
            smean[g] = (red[0] + red[1] + red[2] + red[3]) /
                       (float)(c > 0 ? c : 1);
        }
        __syncthreads();
    }

    const float scr = *scr_p;
    const float soft = *soft_p;
    const float soft2 = soft * soft;

    const int i = i0 + ii;
    const int gi = batch32[i];
    const int si = gstart[gi];
    const unsigned span = (unsigned)(gstart[gi + 1] - si);
    const float pix = pos[3 * i + 0];
    const float piy = pos[3 * i + 1];
    const float piz = pos[3 * i + 2];

    const int jlo = gstart[gfirst];
    const int jhi = gstart[glast + 1];

    float acc = 0.0f;
    for (int jt = jlo; jt < jhi; jt += TJ) {
        __syncthreads();
        const int jj = jt + tid;
        float4 v;
        if (jj < jhi) {
            v.x = pos[3 * jj + 0];
            v.y = pos[3 * jj + 1];
            v.z = pos[3 * jj + 2];
            v.w = q[jj] - smean[batch32[jj]];
        } else {
            v.x = v.y = v.z = v.w = 0.0f;
        }
        tile[tid] = v;
        __syncthreads();

        const int cnt = min(TJ, jhi - jt);
        const int base = jt - si;               // hoisted mask arithmetic
        const int ue = min(js * TI + TI, cnt);
#pragma unroll 4
        for (int u = js * TI; u < ue; ++u) {
            const float4 p = tile[u];
            const float dx = p.x - pix;
            const float dy = p.y - piy;
            const float dz = p.z - piz;
            float d2 = fmaf(dx, dx, soft2);
            d2 = fmaf(dy, dy, d2);
            d2 = fmaf(dz, dz, d2);
            const float rinv = rsqrtf(d2);
            const float r = d2 * rinv;
            const float e = __expf(-scr * r);
            const float w = ((unsigned)(base + u) < span) ? p.w : 0.0f;
            acc = fmaf(w * e, rinv, acc);
        }
    }
    psum[js * TI + ii] = acc;
    __syncthreads();

    if (tid < TI) {
        float tot = 0.0f;
#pragma unroll
        for (int k = 0; k < JS; ++k) tot += psum[k * TI + tid];
        const float qn = q[i] - smean[gi];
        const float sa = fabsf(soft);
        const float selfk = __expf(-scr * sa) / sa;
        out[i] = 0.5f * qn * (tot - qn * selfk);
    }
}

extern "C" void kernel_launch(void* const* d_in, const int* in_sizes, int n_in,
                              void* d_out, int out_size, void* d_ws, size_t ws_size,
                              hipStream_t stream) {
    const float* x    = (const float*)d_in[0];
    const float* pos  = (const float*)d_in[1];
    // d_in[2] = cell (unused by reference math for nonperiodic path)
    const float* W1   = (const float*)d_in[3];
    const float* b1   = (const float*)d_in[4];
    const float* W2   = (const float*)d_in[5];
    const float* b2   = (const float*)d_in[6];
    const float* scr  = (const float*)d_in[7];
    const float* soft = (const float*)d_in[8];
    const void*  braw = (const void*)d_in[9];

    char* ws = (char*)d_ws;
    int*   batch32 = (int*)(ws + OFF_BATCH32);
    float* q       = (float*)(ws + OFF_Q);
    int*   gstart  = (int*)(ws + OFF_GSTART);
    float* out     = (float*)d_out;

    fused1_kernel<<<2049, 256, 0, stream>>>(x, W1, b1, W2, b2, braw,
                                            batch32, gstart, q);
    pairfin_kernel<<<NATOMS / TI, 256, 0, stream>>>(pos, q, batch32, gstart,
                                                    out, scr, soft);
}

// Round 8
// 99.031 us; speedup vs baseline: 1.8625x; 1.0458x over previous
//
#include <hip/hip_runtime.h>
#include <math.h>

#define NATOMS 8192
#define NF 128
#define NH 64
#define NB 8

#define TI 16       // i-atoms per pairfin block
#define TJ 256      // j-tile size (LDS)
#define JS 16       // j-slices per block (TI*JS = 256 threads)

// workspace byte offsets
#define OFF_Q       0         // float[NATOMS]   32 KB
#define OFF_GSTART  32768     // int[NB+1]

// NOTE (R6 post-mortem): do NOT fuse these two kernels with a cooperative
// grid.sync() — measured +75us of stall (device-scope fence/L2 maintenance
// + spin barrier on 8 XCDs) vs ~5us saved launch gap.

// Width detect: sorted non-negative batch => v32[N-1]==0 <=> int64 layout
// (all-zero batch is width-invariant).
__device__ __forceinline__ int batch_at(const int* v32, const long long* v64,
                                        bool is64, int i) {
    return is64 ? (int)v64[i] : v32[i];
}

// ---------------------------------------------------------------------------
// fused1: blocks 0..511 -> q, 4 waves x 4 atoms/wave (W1 loads shared across
//         4 FMA chains: 4x less L1 traffic than wave-per-atom, 4x ILP);
//         block 512     -> gstart binary searches on the raw batch buffer.
// ---------------------------------------------------------------------------
__global__ __launch_bounds__(256) void fused1_kernel(
    const float* __restrict__ x, const float* __restrict__ W1,
    const float* __restrict__ b1, const float* __restrict__ W2,
    const float* __restrict__ b2, const void* __restrict__ batch_raw,
    int* __restrict__ gstart, float* __restrict__ q) {
    const int* v32 = (const int*)batch_raw;
    const long long* v64 = (const long long*)batch_raw;
    const int tid = threadIdx.x;

    if (blockIdx.x == 512) {                    // gstart block
        const bool is64 = (v32[NATOMS - 1] == 0);
        if (tid <= NB) {
            if (tid == NB) {
                gstart[NB] = NATOMS;
            } else {
                int lo = 0, hi = NATOMS;        // lower_bound(batch, tid)
                while (lo < hi) {
                    int mid = (lo + hi) >> 1;
                    if (batch_at(v32, v64, is64, mid) < tid) lo = mid + 1;
                    else hi = mid;
                }
                gstart[tid] = lo;
            }
        }
        return;
    }

    const int wave = tid >> 6;
    const int lane = tid & 63;
    const int a0 = (blockIdx.x * 4 + wave) * 4; // 4 atoms per wave

    const float* xr0 = x + (a0 + 0) * NF;
    const float* xr1 = x + (a0 + 1) * NF;
    const float* xr2 = x + (a0 + 2) * NF;
    const float* xr3 = x + (a0 + 3) * NF;
    const float bb = b1[lane];
    float z0 = bb, z1 = bb, z2 = bb, z3 = bb;
#pragma unroll
    for (int f = 0; f < NF; f += 4) {
        const float4 xa = *(const float4*)(xr0 + f);
        const float4 xb = *(const float4*)(xr1 + f);
        const float4 xc = *(const float4*)(xr2 + f);
        const float4 xd = *(const float4*)(xr3 + f);
        const float w0 = W1[(f + 0) * NH + lane];
        const float w1 = W1[(f + 1) * NH + lane];
        const float w2 = W1[(f + 2) * NH + lane];
        const float w3 = W1[(f + 3) * NH + lane];
        z0 = fmaf(xa.x, w0, z0); z1 = fmaf(xb.x, w0, z1);
        z2 = fmaf(xc.x, w0, z2); z3 = fmaf(xd.x, w0, z3);
        z0 = fmaf(xa.y, w1, z0); z1 = fmaf(xb.y, w1, z1);
        z2 = fmaf(xc.y, w1, z2); z3 = fmaf(xd.y, w1, z3);
        z0 = fmaf(xa.z, w2, z0); z1 = fmaf(xb.z, w2, z1);
        z2 = fmaf(xc.z, w2, z2); z3 = fmaf(xd.z, w2, z3);
        z0 = fmaf(xa.w, w3, z0); z1 = fmaf(xb.w, w3, z1);
        z2 = fmaf(xc.w, w3, z2); z3 = fmaf(xd.w, w3, z3);
    }
    const float wl = W2[lane];
    float t0 = wl * (z0 / (1.0f + __expf(-z0)));   // SiLU then W2 dot
    float t1 = wl * (z1 / (1.0f + __expf(-z1)));
    float t2 = wl * (z2 / (1.0f + __expf(-z2)));
    float t3 = wl * (z3 / (1.0f + __expf(-z3)));
#pragma unroll
    for (int m = 32; m >= 1; m >>= 1) {
        t0 += __shfl_xor(t0, m, 64);
        t1 += __shfl_xor(t1, m, 64);
        t2 += __shfl_xor(t2, m, 64);
        t3 += __shfl_xor(t3, m, 64);
    }
    if (lane == 0) {
        const float bo = b2[0];
        *(float4*)(q + a0) = make_float4(t0 + bo, t1 + bo, t2 + bo, t3 + bo);
    }
}

// ---------------------------------------------------------------------------
// pairfin: 512 blocks x 256 thr = TI(16) i-atoms x JS(16) j-slices.
// Reads the raw batch buffer directly (uniform width select). Preamble:
// per-block graph-sum reduction (batch sorted => contiguous spans). LDS
// j-tiles hold (pos.xyz, qn). Self term included then subtracted
// analytically; no atomics; writes out[].
// ---------------------------------------------------------------------------
__global__ __launch_bounds__(256) void pairfin_kernel(
    const float* __restrict__ pos, const float* __restrict__ q,
    const void* __restrict__ batch_raw, const int* __restrict__ gstart,
    float* __restrict__ out,
    const float* __restrict__ scr_p, const float* __restrict__ soft_p) {
    __shared__ float4 tile[TJ];
    __shared__ float smean[NB];
    __shared__ float red[4];
    __shared__ float psum[JS * TI];

    const int* v32 = (const int*)batch_raw;
    const long long* v64 = (const long long*)batch_raw;
    const bool is64 = (v32[NATOMS - 1] == 0);

    const int tid = threadIdx.x;
    const int ii = tid & (TI - 1);
    const int js = tid >> 4;                    // log2(TI) = 4

    const int i0 = blockIdx.x * TI;
    const int gfirst = batch_at(v32, v64, is64, i0);
    const int glast = batch_at(v32, v64, is64, i0 + TI - 1);

    // per-block graph mean(s): reduce q over each contiguous graph span
    for (int g = gfirst; g <= glast; ++g) {
        const int s = gstart[g], e = gstart[g + 1];
        float t = 0.0f;
        for (int idx = s + tid; idx < e; idx += 256) t += q[idx];
#pragma unroll
        for (int m = 32; m >= 1; m >>= 1) t += __shfl_xor(t, m, 64);
        if ((tid & 63) == 0) red[tid >> 6] = t;
        __syncthreads();
        if (tid == 0) {
            const int c = e - s;
            smean[g] = (red[0] + red[1] + red[2] + red[3]) /
                       (float)(c > 0 ? c : 1);
        }
        __syncthreads();
    }

    const float scr = *scr_p;
    const float soft = *soft_p;
    const float soft2 = soft * soft;

    const int i = i0 + ii;
    const int gi = batch_at(v32, v64, is64, i);
    const int si = gstart[gi];
    const unsigned span = (unsigned)(gstart[gi + 1] - si);
    const float pix = pos[3 * i + 0];
    const float piy = pos[3 * i + 1];
    const float piz = pos[3 * i + 2];

    const int jlo = gstart[gfirst];
    const int jhi = gstart[glast + 1];

    float acc = 0.0f;
    for (int jt = jlo; jt < jhi; jt += TJ) {
        __syncthreads();
        const int jj = jt + tid;
        float4 v;
        if (jj < jhi) {
            v.x = pos[3 * jj + 0];
            v.y = pos[3 * jj + 1];
            v.z = pos[3 * jj + 2];
            v.w = q[jj] - smean[batch_at(v32, v64, is64, jj)];
        } else {
            v.x = v.y = v.z = v.w = 0.0f;
        }
        tile[tid] = v;
        __syncthreads();

        const int cnt = min(TJ, jhi - jt);
        const int base = jt - si;               // hoisted mask arithmetic
        const int ue = min(js * TI + TI, cnt);
#pragma unroll 4
        for (int u = js * TI; u < ue; ++u) {
            const float4 p = tile[u];
            const float dx = p.x - pix;
            const float dy = p.y - piy;
            const float dz = p.z - piz;
            float d2 = fmaf(dx, dx, soft2);
            d2 = fmaf(dy, dy, d2);
            d2 = fmaf(dz, dz, d2);
            const float rinv = rsqrtf(d2);
            const float r = d2 * rinv;
            const float e = __expf(-scr * r);
            const float w = ((unsigned)(base + u) < span) ? p.w : 0.0f;
            acc = fmaf(w * e, rinv, acc);
        }
    }
    psum[js * TI + ii] = acc;
    __syncthreads();

    if (tid < TI) {
        float tot = 0.0f;
#pragma unroll
        for (int k = 0; k < JS; ++k) tot += psum[k * TI + tid];
        const float qn = q[i] - smean[gi];
        const float sa = fabsf(soft);
        const float selfk = __expf(-scr * sa) / sa;
        out[i] = 0.5f * qn * (tot - qn * selfk);
    }
}

extern "C" void kernel_launch(void* const* d_in, const int* in_sizes, int n_in,
                              void* d_out, int out_size, void* d_ws, size_t ws_size,
                              hipStream_t stream) {
    const float* x    = (const float*)d_in[0];
    const float* pos  = (const float*)d_in[1];
    // d_in[2] = cell (unused by reference math for nonperiodic path)
    const float* W1   = (const float*)d_in[3];
    const float* b1   = (const float*)d_in[4];
    const float* W2   = (const float*)d_in[5];
    const float* b2   = (const float*)d_in[6];
    const float* scr  = (const float*)d_in[7];
    const float* soft = (const float*)d_in[8];
    const void*  braw = (const void*)d_in[9];

    char* ws = (char*)d_ws;
    float* q       = (float*)(ws + OFF_Q);
    int*   gstart  = (int*)(ws + OFF_GSTART);
    float* out     = (float*)d_out;

    fused1_kernel<<<513, 256, 0, stream>>>(x, W1, b1, W2, b2, braw,
                                           gstart, q);
    pairfin_kernel<<<NATOMS / TI, 256, 0, stream>>>(pos, q, braw, gstart,
                                                    out, scr, soft);
}